// Round 5
// baseline (1679.587 us; speedup 1.0000x reference)
//
#include <hip/hip_runtime.h>
#include <math.h>
#include <float.h>

#define BGRAPH 16
#define NPTS   2048
#define CDIM   16
#define ODIM   64
#define KNN    16
#define NTOT   (BGRAPH*NPTS)     // 32768
#define NEDGE  (NTOT*KNN)        // 524288
#define EPSBN  1e-5f
#define NBLK_E 2048              // blocks for edge-stat passes
#define NPW    4                 // nodes per wave in edge-stat passes

// ---------------- P = x@W1b, Q = x@(W1a-W1b)+b1, sq = rowsum(x*x) ----------
__global__ __launch_bounds__(256) void pq_kernel(
    const float* __restrict__ x, const float* __restrict__ W1,
    const float* __restrict__ b1,
    float* __restrict__ P, float* __restrict__ Q, float* __restrict__ sq) {
  int lane = threadIdx.x & 63;
  int nin  = threadIdx.x >> 6;           // node within block (0..3)
  int node = blockIdx.x * 4 + nin;
  __shared__ float xs[4][CDIM];
  if (threadIdx.x < 4*CDIM) {
    int n = threadIdx.x / CDIM, c = threadIdx.x % CDIM;
    xs[n][c] = x[(blockIdx.x*4 + n)*CDIM + c];
  }
  __syncthreads();
  float p = 0.f, q = b1[lane];
  #pragma unroll
  for (int c = 0; c < CDIM; ++c) {
    float xv = xs[nin][c];
    float wb = W1[(c+CDIM)*ODIM + lane];
    float wa = W1[c*ODIM + lane];
    p += xv * wb;
    q += xv * (wa - wb);
  }
  P[node*ODIM + lane] = p;
  Q[node*ODIM + lane] = q;
  if (lane == 0) {
    float s = 0.f;
    #pragma unroll
    for (int c = 0; c < CDIM; ++c) { float xv = xs[nin][c]; s += xv*xv; }
    sq[node] = s;
  }
}

// ---------------- kNN: 2 rows/wave, macro-forced static indexing ------------
// LDS-pipe bound (r1 model verified: ~2280 LDS cyc/wave, 128 waves/CU ->
// 121us). Tile reads are SHARED by a wave's rows -> R rows/wave divides LDS
// time by R. r2-r4 failed: d[2][32] landed in scratch (2GB WRITE) despite
// unroll pragmas. This version removes every compiler-dependence: two FLAT
// d0[32]/d1[32] (the r1-proven promotable shape), t-loop macro-expanded
// (TILE(0..7): all d indices literal), selection macro-duplicated per row.
// Row feats wave-uniform -> SGPRs via readfirstlane (r3/r4: SGPR=112 ok).
// tsq omitted: uniform per-row shift preserves ordering (r2-r4 passed).
#define KROWS 8
__device__ __forceinline__ unsigned long long packkey(float dv, int j) {
  unsigned ub = __float_as_uint(dv);
  ub ^= ((unsigned)((int)ub >> 31)) | 0x80000000u;   // monotone f32->u32
  return (((unsigned long long)ub) << 32) | (unsigned)j;
}
__device__ __forceinline__ float rfl(float v) {
  return __uint_as_float(__builtin_amdgcn_readfirstlane(__float_as_uint(v)));
}

#define TILE(T) do {                                                          \
    __syncthreads();                                                          \
    const float4* xp = (const float4*)(x + (size_t)(gbase + (T)*256 + tid)*CDIM); \
    float4 a0 = xp[0], a1 = xp[1], a2 = xp[2], a3 = xp[3];                    \
    sT16[0][tid]=a0.x;  sT16[1][tid]=a0.y;  sT16[2][tid]=a0.z;  sT16[3][tid]=a0.w;  \
    sT16[4][tid]=a1.x;  sT16[5][tid]=a1.y;  sT16[6][tid]=a1.z;  sT16[7][tid]=a1.w;  \
    sT16[8][tid]=a2.x;  sT16[9][tid]=a2.y;  sT16[10][tid]=a2.z; sT16[11][tid]=a2.w; \
    sT16[12][tid]=a3.x; sT16[13][tid]=a3.y; sT16[14][tid]=a3.z; sT16[15][tid]=a3.w; \
    __syncthreads();                                                          \
    float4 sq4 = *(const float4*)(sq + gbase + (T)*256 + 4*lane);             \
    float dA0=0.f,dA1=0.f,dA2=0.f,dA3=0.f;                                    \
    float dB0=0.f,dB1=0.f,dB2=0.f,dB3=0.f;                                    \
    _Pragma("unroll")                                                         \
    for (int c = 0; c < CDIM; ++c) {                                          \
      float4 cv = *(const float4*)(&sT16[c][4*lane]);                         \
      float xa = sga[c], xb = sgb[c];                                         \
      dA0 += xa*cv.x; dA1 += xa*cv.y; dA2 += xa*cv.z; dA3 += xa*cv.w;         \
      dB0 += xb*cv.x; dB1 += xb*cv.y; dB2 += xb*cv.z; dB3 += xb*cv.w;         \
    }                                                                         \
    d0[(T)*4+0] = sq4.x - 2.f*dA0; d0[(T)*4+1] = sq4.y - 2.f*dA1;             \
    d0[(T)*4+2] = sq4.z - 2.f*dA2; d0[(T)*4+3] = sq4.w - 2.f*dA3;             \
    d1[(T)*4+0] = sq4.x - 2.f*dB0; d1[(T)*4+1] = sq4.y - 2.f*dB1;             \
    d1[(T)*4+2] = sq4.z - 2.f*dB2; d1[(T)*4+3] = sq4.w - 2.f*dB3;             \
  } while (0)

#define SELECT(dd, RP) do {                                                   \
    float lmin = dd[0];                                                       \
    _Pragma("unroll")                                                         \
    for (int s = 1; s < 32; ++s) lmin = fminf(lmin, dd[s]);                   \
    float v = lmin;                                                           \
    _Pragma("unroll")                                                         \
    for (int k = 2; k <= 64; k <<= 1) {                                       \
      _Pragma("unroll")                                                       \
      for (int j = k >> 1; j > 0; j >>= 1) {                                  \
        float o = __shfl_xor(v, j);                                           \
        bool asc   = ((lane & k) == 0);                                       \
        bool lower = ((lane & j) == 0);                                       \
        float mn = fminf(v, o), mx = fmaxf(v, o);                             \
        v = (asc == lower) ? mn : mx;                                         \
      }                                                                       \
    }                                                                         \
    float T = __shfl(v, 15);                                                  \
    if (lane == 0) scnt[w] = 0;                                               \
    _Pragma("unroll")                                                         \
    for (int s = 0; s < 32; ++s) {                                            \
      if (dd[s] <= T) {                                                       \
        int p = atomicAdd(&scnt[w], 1);                                       \
        if (p < 64) {                                                         \
          int j = (s >> 2)*256 + 4*lane + (s & 3);                            \
          skey[w][p] = packkey(dd[s], j);                                     \
        }                                                                     \
      }                                                                       \
    }                                                                         \
    int M = scnt[w];                                                          \
    int row = gbase + r0 + (RP);                                              \
    if (M <= 64) {                                                            \
      unsigned long long key = (lane < M) ? skey[w][lane] : ~0ull;            \
      _Pragma("unroll")                                                       \
      for (int k = 2; k <= 64; k <<= 1) {                                     \
        _Pragma("unroll")                                                     \
        for (int j = k >> 1; j > 0; j >>= 1) {                                \
          unsigned long long o = __shfl_xor(key, j);                          \
          bool asc   = ((lane & k) == 0);                                     \
          bool lower = ((lane & j) == 0);                                     \
          unsigned long long mn = (key < o) ? key : o;                        \
          unsigned long long mx = (key < o) ? o : key;                        \
          key = (asc == lower) ? mn : mx;                                     \
        }                                                                     \
      }                                                                       \
      if (lane < KNN)                                                         \
        idxOut[(size_t)row*KNN + lane] = gbase + (int)(key & 0xffffffffu);    \
    } else {                                                                  \
      for (int sel = 0; sel < KNN; ++sel) {                                   \
        unsigned long long lb = ~0ull;                                        \
        _Pragma("unroll")                                                     \
        for (int s = 0; s < 32; ++s) {                                        \
          int j = (s >> 2)*256 + 4*lane + (s & 3);                            \
          unsigned long long ks = packkey(dd[s], j);                          \
          if (ks < lb) lb = ks;                                               \
        }                                                                     \
        _Pragma("unroll")                                                     \
        for (int off = 32; off > 0; off >>= 1) {                              \
          unsigned long long o = __shfl_xor(lb, off);                         \
          if (o < lb) lb = o;                                                 \
        }                                                                     \
        if (lane == 0)                                                        \
          idxOut[(size_t)row*KNN + sel] = gbase + (int)(lb & 0xffffffffu);    \
        _Pragma("unroll")                                                     \
        for (int s = 0; s < 32; ++s) {                                        \
          int j = (s >> 2)*256 + 4*lane + (s & 3);                            \
          if (packkey(dd[s], j) == lb) dd[s] = FLT_MAX;                       \
        }                                                                     \
      }                                                                       \
    }                                                                         \
  } while (0)

__global__ __launch_bounds__(256, 3) void knn_kernel(
    const float* __restrict__ x, const float* __restrict__ sq,
    int* __restrict__ idxOut) {
  __shared__ float sT16[CDIM][256];                 // transposed tile, 16 KB
  __shared__ unsigned long long skey[4][64];        // per-wave survivor keys
  __shared__ int scnt[4];
  const int tid  = threadIdx.x;
  const int lane = tid & 63;
  const int w    = tid >> 6;
  const int blocksPerGraph = NPTS / KROWS;          // 256
  const int g     = blockIdx.x / blocksPerGraph;
  const int rb    = (blockIdx.x % blocksPerGraph) * KROWS;
  const int gbase = g * NPTS;
  const int r0    = rb + w*2;                       // this wave's rows r0,r0+1

  // wave-uniform row features -> SGPRs
  float sga[CDIM], sgb[CDIM];
  {
    const float4* tp = (const float4*)(x + (size_t)(gbase + r0)*CDIM);
    float4 t0 = tp[0], t1 = tp[1], t2 = tp[2], t3 = tp[3];
    sga[0]=rfl(t0.x);  sga[1]=rfl(t0.y);  sga[2]=rfl(t0.z);  sga[3]=rfl(t0.w);
    sga[4]=rfl(t1.x);  sga[5]=rfl(t1.y);  sga[6]=rfl(t1.z);  sga[7]=rfl(t1.w);
    sga[8]=rfl(t2.x);  sga[9]=rfl(t2.y);  sga[10]=rfl(t2.z); sga[11]=rfl(t2.w);
    sga[12]=rfl(t3.x); sga[13]=rfl(t3.y); sga[14]=rfl(t3.z); sga[15]=rfl(t3.w);
    const float4* up = (const float4*)(x + (size_t)(gbase + r0 + 1)*CDIM);
    float4 u0 = up[0], u1 = up[1], u2 = up[2], u3 = up[3];
    sgb[0]=rfl(u0.x);  sgb[1]=rfl(u0.y);  sgb[2]=rfl(u0.z);  sgb[3]=rfl(u0.w);
    sgb[4]=rfl(u1.x);  sgb[5]=rfl(u1.y);  sgb[6]=rfl(u1.z);  sgb[7]=rfl(u1.w);
    sgb[8]=rfl(u2.x);  sgb[9]=rfl(u2.y);  sgb[10]=rfl(u2.z); sgb[11]=rfl(u2.w);
    sgb[12]=rfl(u3.x); sgb[13]=rfl(u3.y); sgb[14]=rfl(u3.z); sgb[15]=rfl(u3.w);
  }

  float d0[32], d1[32];

  TILE(0); TILE(1); TILE(2); TILE(3);
  TILE(4); TILE(5); TILE(6); TILE(7);

  SELECT(d0, 0);
  SELECT(d1, 1);
}

// ---------------- stats pass 1: per-channel sum/sumsq of h ------------------
// 2048 blocks x 4 waves; 4 nodes/wave; partials -> pbuf[chanstat][block]
__global__ __launch_bounds__(256) void stats1_kernel(
    const float* __restrict__ P, const float* __restrict__ Q,
    const int* __restrict__ idx, float* __restrict__ pbuf) {
  int lane = threadIdx.x & 63;
  int wid  = threadIdx.x >> 6;
  int gw   = blockIdx.x * 4 + wid;
  int n0 = gw * NPW;
  float s = 0.f, ss = 0.f;
  #pragma unroll
  for (int ii = 0; ii < NPW; ++ii) {
    int i = n0 + ii;
    float qv = Q[(size_t)i*ODIM + lane];
    #pragma unroll
    for (int k = 0; k < KNN; ++k) {
      int j = idx[(size_t)i*KNN + k];
      float h = qv + P[(size_t)j*ODIM + lane];
      s += h; ss += h*h;
    }
  }
  __shared__ float ls[4][ODIM], lss[4][ODIM];
  ls[wid][lane] = s; lss[wid][lane] = ss;
  __syncthreads();
  int tid = threadIdx.x;
  if (tid < ODIM) {
    float a = ls[0][tid] + ls[1][tid] + ls[2][tid] + ls[3][tid];
    pbuf[(size_t)tid*NBLK_E + blockIdx.x] = a;
  } else if (tid < 2*ODIM) {
    int o = tid - ODIM;
    float a = lss[0][o] + lss[1][o] + lss[2][o] + lss[3][o];
    pbuf[(size_t)(ODIM+o)*NBLK_E + blockIdx.x] = a;
  }
}

// 64 blocks x 1 wave: block o reduces channel o's sum & sumsq rows of pbuf
__global__ __launch_bounds__(64) void fin1_kernel(
    const float* __restrict__ pbuf,
    const float* __restrict__ g1, const float* __restrict__ be1,
    float* __restrict__ scale, float* __restrict__ shift) {
  int o = blockIdx.x, lane = threadIdx.x;
  const float* ps = pbuf + (size_t)o*NBLK_E;
  const float* pq = pbuf + (size_t)(ODIM+o)*NBLK_E;
  float s = 0.f, ss = 0.f;
  for (int t = lane; t < NBLK_E; t += 64) { s += ps[t]; ss += pq[t]; }
  #pragma unroll
  for (int off = 32; off > 0; off >>= 1) {
    s  += __shfl_xor(s, off);
    ss += __shfl_xor(ss, off);
  }
  if (lane == 0) {
    float mu  = s / (float)NEDGE;
    float var = ss / (float)NEDGE - mu*mu;
    float inv = 1.0f / sqrtf(var + EPSBN);
    float sc = g1[o] * inv;
    scale[o] = sc;
    shift[o] = be1[o] - mu * sc;
  }
}

// ---------------- stats pass 2: gate values + scalar sum/sumsq --------------
__global__ __launch_bounds__(256) void stats2_kernel(
    const float* __restrict__ P, const float* __restrict__ Q,
    const int* __restrict__ idx, const float* __restrict__ scale,
    const float* __restrict__ shift, const float* __restrict__ Wg,
    const float* __restrict__ bg, float* __restrict__ gtbuf,
    float* __restrict__ gpart) {
  int lane = threadIdx.x & 63;
  int wid  = threadIdx.x >> 6;
  int gw   = blockIdx.x * 4 + wid;
  int n0 = gw * NPW;
  float sc = scale[lane], sh = shift[lane], wg = Wg[lane], bgv = bg[0];
  float s = 0.f, ss = 0.f;
  #pragma unroll
  for (int ii = 0; ii < NPW; ++ii) {
    int i = n0 + ii;
    float qv = Q[(size_t)i*ODIM + lane];
    #pragma unroll
    for (int k = 0; k < KNN; ++k) {
      int j = idx[(size_t)i*KNN + k];
      float z = (qv + P[(size_t)j*ODIM + lane]) * sc + sh;
      float hn = z / (1.f + expf(-z));
      float v = hn * wg;
      #pragma unroll
      for (int off = 32; off > 0; off >>= 1) v += __shfl_xor(v, off);
      float g = v + bgv;               // full sum on all lanes after butterfly
      if (lane == 0) {
        gtbuf[(size_t)i*KNN + k] = g;
        s += g; ss += g*g;
      }
    }
  }
  __shared__ float pw[4], pws[4];
  if (lane == 0) { pw[wid] = s; pws[wid] = ss; }
  __syncthreads();
  if (threadIdx.x == 0) {
    gpart[2*blockIdx.x]   = pw[0]+pw[1]+pw[2]+pw[3];
    gpart[2*blockIdx.x+1] = pws[0]+pws[1]+pws[2]+pws[3];
  }
}

// 1 block x 256: reduce 2048 (s,ss) pairs -> gate BN scale/shift
__global__ __launch_bounds__(256) void fin2_kernel(
    const float* __restrict__ gpart,
    const float* __restrict__ gg, const float* __restrict__ beg,
    float* __restrict__ gsc) {
  int tid = threadIdx.x;
  float s = 0.f, ss = 0.f;
  for (int t = tid; t < NBLK_E; t += 256) { s += gpart[2*t]; ss += gpart[2*t+1]; }
  __shared__ float as[256], bs[256];
  as[tid] = s; bs[tid] = ss;
  __syncthreads();
  #pragma unroll
  for (int st = 128; st > 0; st >>= 1) {
    if (tid < st) { as[tid] += as[tid+st]; bs[tid] += bs[tid+st]; }
    __syncthreads();
  }
  if (tid == 0) {
    float mu  = as[0] / (float)NEDGE;
    float var = bs[0] / (float)NEDGE - mu*mu;
    float inv = 1.f / sqrtf(var + EPSBN);
    float sg = gg[0] * inv;
    gsc[0] = sg; gsc[1] = beg[0] - mu * sg;
  }
}

// ---------------- final: hn, gate from gtbuf, softmax over K, weighted sum --
__global__ __launch_bounds__(256) void final_kernel(
    const float* __restrict__ P, const float* __restrict__ Q,
    const int* __restrict__ idx, const float* __restrict__ scale,
    const float* __restrict__ shift, const float* __restrict__ gtbuf,
    const float* __restrict__ gsc, float* __restrict__ out) {
  int lane = threadIdx.x & 63;
  int wid  = threadIdx.x >> 6;
  int i = blockIdx.x * 4 + wid;
  float sc = scale[lane], sh = shift[lane];
  float gscale = gsc[0], gshift = gsc[1];
  float qv = Q[(size_t)i*ODIM + lane];
  float hn[KNN], gt[KNN];
  #pragma unroll
  for (int k = 0; k < KNN; ++k) {
    int j = idx[(size_t)i*KNN + k];
    float z = (qv + P[(size_t)j*ODIM + lane]) * sc + sh;
    hn[k] = z / (1.f + expf(-z));
    float g = gtbuf[(size_t)i*KNN + k];
    float zg = g * gscale + gshift;
    gt[k] = zg / (1.f + expf(-zg));
  }
  float m = gt[0];
  #pragma unroll
  for (int k = 1; k < KNN; ++k) m = fmaxf(m, gt[k]);
  float se = 0.f;
  #pragma unroll
  for (int k = 0; k < KNN; ++k) { gt[k] = expf(gt[k] - m); se += gt[k]; }
  float invs = 1.f / se;
  float acc = 0.f;
  #pragma unroll
  for (int k = 0; k < KNN; ++k) acc += gt[k] * invs * hn[k];
  out[(size_t)i*ODIM + lane] = acc;
}

extern "C" void kernel_launch(void* const* d_in, const int* in_sizes, int n_in,
                              void* d_out, int out_size, void* d_ws, size_t ws_size,
                              hipStream_t stream) {
  const float* x   = (const float*)d_in[0];
  // d_in[1] = batch (unused: sorted equal-size graphs)
  const float* W1  = (const float*)d_in[2];
  const float* b1  = (const float*)d_in[3];
  const float* g1  = (const float*)d_in[4];
  const float* be1 = (const float*)d_in[5];
  const float* Wg  = (const float*)d_in[6];
  const float* bg  = (const float*)d_in[7];
  const float* gg  = (const float*)d_in[8];
  const float* beg = (const float*)d_in[9];
  float* out = (float*)d_out;

  char* ws = (char*)d_ws;
  int*   idx   = (int*)  (ws);                         // 2 MB
  float* P     = (float*)(ws + 2097152);               // 8 MB
  float* Q     = (float*)(ws + 10485760);              // 8 MB
  float* sq    = (float*)(ws + 18874368);              // 128 KB
  float* pbuf  = (float*)(ws + 19005440);              // 1 MB   [128][2048]
  float* gpart = (float*)(ws + 20054016);              // 16 KB  [2048][2]
  float* gtbuf = (float*)(ws + 20070400);              // 2 MB   [NEDGE]
  float* scale = (float*)(ws + 22167552);              // 64 f
  float* shift = (float*)(ws + 22167808);              // 64 f
  float* gsc   = (float*)(ws + 22168064);              // 2 f

  pq_kernel<<<NTOT/4, 256, 0, stream>>>(x, W1, b1, P, Q, sq);
  knn_kernel<<<NTOT/KROWS, 256, 0, stream>>>(x, sq, idx);
  stats1_kernel<<<NBLK_E, 256, 0, stream>>>(P, Q, idx, pbuf);
  fin1_kernel<<<ODIM, 64, 0, stream>>>(pbuf, g1, be1, scale, shift);
  stats2_kernel<<<NBLK_E, 256, 0, stream>>>(P, Q, idx, scale, shift, Wg, bg, gtbuf, gpart);
  fin2_kernel<<<1, 256, 0, stream>>>(gpart, gg, beg, gsc);
  final_kernel<<<NTOT/4, 256, 0, stream>>>(P, Q, idx, scale, shift, gtbuf, gsc, out);
}

// Round 6
// 305.402 us; speedup vs baseline: 5.4996x; 5.4996x over previous
//
#include <hip/hip_runtime.h>
#include <math.h>
#include <float.h>

#define BGRAPH 16
#define NPTS   2048
#define CDIM   16
#define ODIM   64
#define KNN    16
#define NTOT   (BGRAPH*NPTS)     // 32768
#define NEDGE  (NTOT*KNN)        // 524288
#define EPSBN  1e-5f
#define NBLK_E 2048              // blocks for edge-stat passes
#define NPW    4                 // nodes per wave in edge-stat passes

// ---------------- P = x@W1b, Q = x@(W1a-W1b)+b1, sq = rowsum(x*x) ----------
__global__ __launch_bounds__(256) void pq_kernel(
    const float* __restrict__ x, const float* __restrict__ W1,
    const float* __restrict__ b1,
    float* __restrict__ P, float* __restrict__ Q, float* __restrict__ sq) {
  int lane = threadIdx.x & 63;
  int nin  = threadIdx.x >> 6;           // node within block (0..3)
  int node = blockIdx.x * 4 + nin;
  __shared__ float xs[4][CDIM];
  if (threadIdx.x < 4*CDIM) {
    int n = threadIdx.x / CDIM, c = threadIdx.x % CDIM;
    xs[n][c] = x[(blockIdx.x*4 + n)*CDIM + c];
  }
  __syncthreads();
  float p = 0.f, q = b1[lane];
  #pragma unroll
  for (int c = 0; c < CDIM; ++c) {
    float xv = xs[nin][c];
    float wb = W1[(c+CDIM)*ODIM + lane];
    float wa = W1[c*ODIM + lane];
    p += xv * wb;
    q += xv * (wa - wb);
  }
  P[node*ODIM + lane] = p;
  Q[node*ODIM + lane] = q;
  if (lane == 0) {
    float s = 0.f;
    #pragma unroll
    for (int c = 0; c < CDIM; ++c) { float xv = xs[nin][c]; s += xv*xv; }
    sq[node] = s;
  }
}

// ---------------- kNN: one row per wave, all state in registers -------------
// REVERTED to the round-1 verbatim kernel (measured: 123us, VGPR=56,
// WRITE_SIZE=2MB). Every R=2 attempt (r2-r5: 2D array, unroll pragmas,
// macro-forced flat arrays) put the distance array in scratch (2GB WRITE,
// 7-11x slower). Flat d[32] + ~56 VGPR total demand is the proven-promotable
// shape on this compiler. Do not increase per-thread state here.
#define KROWS 4
__device__ __forceinline__ unsigned long long packkey(float dv, int j) {
  unsigned ub = __float_as_uint(dv);
  ub ^= ((unsigned)((int)ub >> 31)) | 0x80000000u;   // monotone f32->u32
  return (((unsigned long long)ub) << 32) | (unsigned)j;
}

__global__ __launch_bounds__(256, 4) void knn_kernel(
    const float* __restrict__ x, const float* __restrict__ sq,
    int* __restrict__ idxOut) {
  __shared__ float sT16[CDIM][256];                 // transposed tile, 16 KB
  __shared__ unsigned long long skey[4][64];        // per-wave survivor keys
  __shared__ int scnt[4];
  const int tid  = threadIdx.x;
  const int lane = tid & 63;
  const int w    = tid >> 6;
  const int blocksPerGraph = NPTS / KROWS;          // 512
  const int g     = blockIdx.x / blocksPerGraph;
  const int rb    = (blockIdx.x % blocksPerGraph) * KROWS;
  const int gbase = g * NPTS;
  const int r0    = rb + w;                         // this wave's single row

  float tg[CDIM]; float tsq;
  {
    const float4* tp = (const float4*)(x + (size_t)(gbase + r0)*CDIM);
    float4 t0 = tp[0], t1 = tp[1], t2 = tp[2], t3 = tp[3];
    tg[0]=t0.x; tg[1]=t0.y; tg[2]=t0.z; tg[3]=t0.w;
    tg[4]=t1.x; tg[5]=t1.y; tg[6]=t1.z; tg[7]=t1.w;
    tg[8]=t2.x; tg[9]=t2.y; tg[10]=t2.z; tg[11]=t2.w;
    tg[12]=t3.x; tg[13]=t3.y; tg[14]=t3.z; tg[15]=t3.w;
    tsq = sq[gbase + r0];
  }

  float d[32];

  // prefetch tile 0 into regs
  float4 a0, a1, a2, a3;
  {
    const float4* xp = (const float4*)(x + (size_t)(gbase + tid)*CDIM);
    a0 = xp[0]; a1 = xp[1]; a2 = xp[2]; a3 = xp[3];
  }

  for (int t = 0; t < NPTS/256; ++t) {
    __syncthreads();                                // prev tile reads done
    sT16[0][tid]=a0.x;  sT16[1][tid]=a0.y;  sT16[2][tid]=a0.z;  sT16[3][tid]=a0.w;
    sT16[4][tid]=a1.x;  sT16[5][tid]=a1.y;  sT16[6][tid]=a1.z;  sT16[7][tid]=a1.w;
    sT16[8][tid]=a2.x;  sT16[9][tid]=a2.y;  sT16[10][tid]=a2.z; sT16[11][tid]=a2.w;
    sT16[12][tid]=a3.x; sT16[13][tid]=a3.y; sT16[14][tid]=a3.z; sT16[15][tid]=a3.w;
    __syncthreads();
    if (t < NPTS/256 - 1) {                         // issue next-tile loads early
      const float4* xp = (const float4*)(x + (size_t)(gbase + (t+1)*256 + tid)*CDIM);
      a0 = xp[0]; a1 = xp[1]; a2 = xp[2]; a3 = xp[3];
    }

    float4 sq4 = *(const float4*)(sq + gbase + t*256 + 4*lane);
    float sqv[4] = {sq4.x, sq4.y, sq4.z, sq4.w};

    float dot[4] = {0.f,0.f,0.f,0.f};
    #pragma unroll
    for (int c = 0; c < CDIM; ++c) {
      float4 cv = *(const float4*)(&sT16[c][4*lane]);
      float cvv[4]; cvv[0]=cv.x; cvv[1]=cv.y; cvv[2]=cv.z; cvv[3]=cv.w;
      float xv = tg[c];
      #pragma unroll
      for (int rr = 0; rr < 4; ++rr)
        dot[rr] += xv * cvv[rr];
    }
    #pragma unroll
    for (int rr = 0; rr < 4; ++rr)
      d[t*4 + rr] = tsq + sqv[rr] - 2.f*dot[rr];
  }

  {
    float lmin = d[0];
    #pragma unroll
    for (int s = 1; s < 32; ++s) lmin = fminf(lmin, d[s]);

    float v = lmin;
    #pragma unroll
    for (int k = 2; k <= 64; k <<= 1) {
      #pragma unroll
      for (int j = k >> 1; j > 0; j >>= 1) {
        float o = __shfl_xor(v, j);
        bool asc   = ((lane & k) == 0);
        bool lower = ((lane & j) == 0);
        float mn = fminf(v, o), mx = fmaxf(v, o);
        v = (asc == lower) ? mn : mx;
      }
    }
    float T = __shfl(v, 15);

    if (lane == 0) scnt[w] = 0;
    #pragma unroll
    for (int s = 0; s < 32; ++s) {
      if (d[s] <= T) {
        int p = atomicAdd(&scnt[w], 1);
        if (p < 64) {
          int j = (s >> 2)*256 + 4*lane + (s & 3);
          skey[w][p] = packkey(d[s], j);
        }
      }
    }
    int M = scnt[w];
    int row = gbase + r0;

    if (M <= 64) {
      unsigned long long key = (lane < M) ? skey[w][lane] : ~0ull;
      #pragma unroll
      for (int k = 2; k <= 64; k <<= 1) {
        #pragma unroll
        for (int j = k >> 1; j > 0; j >>= 1) {
          unsigned long long o = __shfl_xor(key, j);
          bool asc   = ((lane & k) == 0);
          bool lower = ((lane & j) == 0);
          unsigned long long mn = (key < o) ? key : o;
          unsigned long long mx = (key < o) ? o : key;
          key = (asc == lower) ? mn : mx;
        }
      }
      if (lane < KNN)
        idxOut[(size_t)row*KNN + lane] = gbase + (int)(key & 0xffffffffu);
    } else {
      for (int sel = 0; sel < KNN; ++sel) {
        unsigned long long lb = ~0ull;
        #pragma unroll
        for (int s = 0; s < 32; ++s) {
          int j = (s >> 2)*256 + 4*lane + (s & 3);
          unsigned long long ks = packkey(d[s], j);
          if (ks < lb) lb = ks;
        }
        #pragma unroll
        for (int off = 32; off > 0; off >>= 1) {
          unsigned long long o = __shfl_xor(lb, off);
          if (o < lb) lb = o;
        }
        if (lane == 0)
          idxOut[(size_t)row*KNN + sel] = gbase + (int)(lb & 0xffffffffu);
        #pragma unroll
        for (int s = 0; s < 32; ++s) {
          int j = (s >> 2)*256 + 4*lane + (s & 3);
          if (packkey(d[s], j) == lb) d[s] = FLT_MAX;
        }
      }
    }
  }
}

// ---------------- stats pass 1: per-channel sum/sumsq of h ------------------
// 2048 blocks x 4 waves; 4 nodes/wave; partials -> pbuf[chanstat][block]
__global__ __launch_bounds__(256) void stats1_kernel(
    const float* __restrict__ P, const float* __restrict__ Q,
    const int* __restrict__ idx, float* __restrict__ pbuf) {
  int lane = threadIdx.x & 63;
  int wid  = threadIdx.x >> 6;
  int gw   = blockIdx.x * 4 + wid;
  int n0 = gw * NPW;
  float s = 0.f, ss = 0.f;
  #pragma unroll
  for (int ii = 0; ii < NPW; ++ii) {
    int i = n0 + ii;
    float qv = Q[(size_t)i*ODIM + lane];
    #pragma unroll
    for (int k = 0; k < KNN; ++k) {
      int j = idx[(size_t)i*KNN + k];
      float h = qv + P[(size_t)j*ODIM + lane];
      s += h; ss += h*h;
    }
  }
  __shared__ float ls[4][ODIM], lss[4][ODIM];
  ls[wid][lane] = s; lss[wid][lane] = ss;
  __syncthreads();
  int tid = threadIdx.x;
  if (tid < ODIM) {
    float a = ls[0][tid] + ls[1][tid] + ls[2][tid] + ls[3][tid];
    pbuf[(size_t)tid*NBLK_E + blockIdx.x] = a;
  } else if (tid < 2*ODIM) {
    int o = tid - ODIM;
    float a = lss[0][o] + lss[1][o] + lss[2][o] + lss[3][o];
    pbuf[(size_t)(ODIM+o)*NBLK_E + blockIdx.x] = a;
  }
}

// 64 blocks x 1 wave: block o reduces channel o's sum & sumsq rows of pbuf
__global__ __launch_bounds__(64) void fin1_kernel(
    const float* __restrict__ pbuf,
    const float* __restrict__ g1, const float* __restrict__ be1,
    float* __restrict__ scale, float* __restrict__ shift) {
  int o = blockIdx.x, lane = threadIdx.x;
  const float* ps = pbuf + (size_t)o*NBLK_E;
  const float* pq = pbuf + (size_t)(ODIM+o)*NBLK_E;
  float s = 0.f, ss = 0.f;
  for (int t = lane; t < NBLK_E; t += 64) { s += ps[t]; ss += pq[t]; }
  #pragma unroll
  for (int off = 32; off > 0; off >>= 1) {
    s  += __shfl_xor(s, off);
    ss += __shfl_xor(ss, off);
  }
  if (lane == 0) {
    float mu  = s / (float)NEDGE;
    float var = ss / (float)NEDGE - mu*mu;
    float inv = 1.0f / sqrtf(var + EPSBN);
    float sc = g1[o] * inv;
    scale[o] = sc;
    shift[o] = be1[o] - mu * sc;
  }
}

// ---------------- stats pass 2: gate values + scalar sum/sumsq --------------
// GROUPED: wave = 4 groups x 16 lanes; each group owns one edge, each lane
// owns 4 channels (float4). Wg-dot reduction = 4 shfl_xor within a 16-lane
// group, amortized over 4 edges in parallel -> 16 shfl/node vs 96 before
// (shfl = ds_bpermute on the LDS pipe, the old serializer). P gathers become
// dwordx4 (4x fewer load instrs, same bytes). Q loaded once per node.
__global__ __launch_bounds__(256) void stats2_kernel(
    const float* __restrict__ P, const float* __restrict__ Q,
    const int* __restrict__ idx, const float* __restrict__ scale,
    const float* __restrict__ shift, const float* __restrict__ Wg,
    const float* __restrict__ bg, float* __restrict__ gtbuf,
    float* __restrict__ gpart) {
  int lane = threadIdx.x & 63;
  int wid  = threadIdx.x >> 6;
  int grp  = lane >> 4;                 // 0..3 edge slot
  int p    = lane & 15;                 // 0..15 channel quad
  int gw   = blockIdx.x * 4 + wid;
  int n0 = gw * NPW;
  float4 sc4 = *(const float4*)(scale + 4*p);
  float4 sh4 = *(const float4*)(shift + 4*p);
  float4 wg4 = *(const float4*)(Wg + 4*p);
  float bgv = bg[0];
  float s = 0.f, ss = 0.f;
  #pragma unroll
  for (int ii = 0; ii < NPW; ++ii) {
    int i = n0 + ii;
    float4 q4 = *(const float4*)(Q + (size_t)i*ODIM + 4*p);
    #pragma unroll
    for (int k0 = 0; k0 < KNN; k0 += 4) {
      int j = idx[(size_t)i*KNN + k0 + grp];
      float4 p4 = *(const float4*)(P + (size_t)j*ODIM + 4*p);
      float zx = (q4.x + p4.x)*sc4.x + sh4.x;
      float zy = (q4.y + p4.y)*sc4.y + sh4.y;
      float zz = (q4.z + p4.z)*sc4.z + sh4.z;
      float zw = (q4.w + p4.w)*sc4.w + sh4.w;
      float v = (zx/(1.f+expf(-zx)))*wg4.x
              + (zy/(1.f+expf(-zy)))*wg4.y
              + (zz/(1.f+expf(-zz)))*wg4.z
              + (zw/(1.f+expf(-zw)))*wg4.w;
      v += __shfl_xor(v, 1);
      v += __shfl_xor(v, 2);
      v += __shfl_xor(v, 4);
      v += __shfl_xor(v, 8);            // group-wide sum over 64 channels
      float gt = v + bgv;
      if (p == 0) gtbuf[(size_t)i*KNN + k0 + grp] = gt;
      s += gt; ss += gt*gt;             // per-group partial (dup across 16 lanes)
    }
  }
  // combine the 4 groups' partials (each duplicated on its 16 lanes)
  s  += __shfl_xor(s, 16);  s  += __shfl_xor(s, 32);
  ss += __shfl_xor(ss, 16); ss += __shfl_xor(ss, 32);
  __shared__ float pw[4], pws[4];
  if (lane == 0) { pw[wid] = s; pws[wid] = ss; }
  __syncthreads();
  if (threadIdx.x == 0) {
    gpart[2*blockIdx.x]   = pw[0]+pw[1]+pw[2]+pw[3];
    gpart[2*blockIdx.x+1] = pws[0]+pws[1]+pws[2]+pws[3];
  }
}

// 1 block x 256: reduce 2048 (s,ss) pairs -> gate BN scale/shift
__global__ __launch_bounds__(256) void fin2_kernel(
    const float* __restrict__ gpart,
    const float* __restrict__ gg, const float* __restrict__ beg,
    float* __restrict__ gsc) {
  int tid = threadIdx.x;
  float s = 0.f, ss = 0.f;
  for (int t = tid; t < NBLK_E; t += 256) { s += gpart[2*t]; ss += gpart[2*t+1]; }
  __shared__ float as[256], bs[256];
  as[tid] = s; bs[tid] = ss;
  __syncthreads();
  #pragma unroll
  for (int st = 128; st > 0; st >>= 1) {
    if (tid < st) { as[tid] += as[tid+st]; bs[tid] += bs[tid+st]; }
    __syncthreads();
  }
  if (tid == 0) {
    float mu  = as[0] / (float)NEDGE;
    float var = bs[0] / (float)NEDGE - mu*mu;
    float inv = 1.f / sqrtf(var + EPSBN);
    float sg = gg[0] * inv;
    gsc[0] = sg; gsc[1] = beg[0] - mu * sg;
  }
}

// ---------------- final: hn, gate from gtbuf, softmax over K, weighted sum --
__global__ __launch_bounds__(256) void final_kernel(
    const float* __restrict__ P, const float* __restrict__ Q,
    const int* __restrict__ idx, const float* __restrict__ scale,
    const float* __restrict__ shift, const float* __restrict__ gtbuf,
    const float* __restrict__ gsc, float* __restrict__ out) {
  int lane = threadIdx.x & 63;
  int wid  = threadIdx.x >> 6;
  int i = blockIdx.x * 4 + wid;
  float sc = scale[lane], sh = shift[lane];
  float gscale = gsc[0], gshift = gsc[1];
  float qv = Q[(size_t)i*ODIM + lane];
  float hn[KNN], gt[KNN];
  #pragma unroll
  for (int k = 0; k < KNN; ++k) {
    int j = idx[(size_t)i*KNN + k];
    float z = (qv + P[(size_t)j*ODIM + lane]) * sc + sh;
    hn[k] = z / (1.f + expf(-z));
    float g = gtbuf[(size_t)i*KNN + k];
    float zg = g * gscale + gshift;
    gt[k] = zg / (1.f + expf(-zg));
  }
  float m = gt[0];
  #pragma unroll
  for (int k = 1; k < KNN; ++k) m = fmaxf(m, gt[k]);
  float se = 0.f;
  #pragma unroll
  for (int k = 0; k < KNN; ++k) { gt[k] = expf(gt[k] - m); se += gt[k]; }
  float invs = 1.f / se;
  float acc = 0.f;
  #pragma unroll
  for (int k = 0; k < KNN; ++k) acc += gt[k] * invs * hn[k];
  out[(size_t)i*ODIM + lane] = acc;
}

extern "C" void kernel_launch(void* const* d_in, const int* in_sizes, int n_in,
                              void* d_out, int out_size, void* d_ws, size_t ws_size,
                              hipStream_t stream) {
  const float* x   = (const float*)d_in[0];
  // d_in[1] = batch (unused: sorted equal-size graphs)
  const float* W1  = (const float*)d_in[2];
  const float* b1  = (const float*)d_in[3];
  const float* g1  = (const float*)d_in[4];
  const float* be1 = (const float*)d_in[5];
  const float* Wg  = (const float*)d_in[6];
  const float* bg  = (const float*)d_in[7];
  const float* gg  = (const float*)d_in[8];
  const float* beg = (const float*)d_in[9];
  float* out = (float*)d_out;

  char* ws = (char*)d_ws;
  int*   idx   = (int*)  (ws);                         // 2 MB
  float* P     = (float*)(ws + 2097152);               // 8 MB
  float* Q     = (float*)(ws + 10485760);              // 8 MB
  float* sq    = (float*)(ws + 18874368);              // 128 KB
  float* pbuf  = (float*)(ws + 19005440);              // 1 MB   [128][2048]
  float* gpart = (float*)(ws + 20054016);              // 16 KB  [2048][2]
  float* gtbuf = (float*)(ws + 20070400);              // 2 MB   [NEDGE]
  float* scale = (float*)(ws + 22167552);              // 64 f
  float* shift = (float*)(ws + 22167808);              // 64 f
  float* gsc   = (float*)(ws + 22168064);              // 2 f

  pq_kernel<<<NTOT/4, 256, 0, stream>>>(x, W1, b1, P, Q, sq);
  knn_kernel<<<NTOT/KROWS, 256, 0, stream>>>(x, sq, idx);
  stats1_kernel<<<NBLK_E, 256, 0, stream>>>(P, Q, idx, pbuf);
  fin1_kernel<<<ODIM, 64, 0, stream>>>(pbuf, g1, be1, scale, shift);
  stats2_kernel<<<NBLK_E, 256, 0, stream>>>(P, Q, idx, scale, shift, Wg, bg, gtbuf, gpart);
  fin2_kernel<<<1, 256, 0, stream>>>(gpart, gg, beg, gsc);
  final_kernel<<<NTOT/4, 256, 0, stream>>>(P, Q, idx, scale, shift, gtbuf, gsc, out);
}

// Round 9
// 278.739 us; speedup vs baseline: 6.0257x; 1.0957x over previous
//
#include <hip/hip_runtime.h>
#include <math.h>
#include <float.h>

#define BGRAPH 16
#define NPTS   2048
#define CDIM   16
#define ODIM   64
#define KNN    16
#define NTOT   (BGRAPH*NPTS)     // 32768
#define NEDGE  (NTOT*KNN)        // 524288
#define EPSBN  1e-5f
#define NBLK_E 2048              // blocks for edge-stat passes
#define NPW    4                 // nodes per wave in edge-stat passes

// ---------------- P = x@W1b, Q = x@(W1a-W1b)+b1, sq = rowsum(x*x) ----------
__global__ __launch_bounds__(256) void pq_kernel(
    const float* __restrict__ x, const float* __restrict__ W1,
    const float* __restrict__ b1,
    float* __restrict__ P, float* __restrict__ Q, float* __restrict__ sq) {
  int lane = threadIdx.x & 63;
  int nin  = threadIdx.x >> 6;           // node within block (0..3)
  int node = blockIdx.x * 4 + nin;
  __shared__ float xs[4][CDIM];
  if (threadIdx.x < 4*CDIM) {
    int n = threadIdx.x / CDIM, c = threadIdx.x % CDIM;
    xs[n][c] = x[(blockIdx.x*4 + n)*CDIM + c];
  }
  __syncthreads();
  float p = 0.f, q = b1[lane];
  #pragma unroll
  for (int c = 0; c < CDIM; ++c) {
    float xv = xs[nin][c];
    float wb = W1[(c+CDIM)*ODIM + lane];
    float wa = W1[c*ODIM + lane];
    p += xv * wb;
    q += xv * (wa - wb);
  }
  P[node*ODIM + lane] = p;
  Q[node*ODIM + lane] = q;
  if (lane == 0) {
    float s = 0.f;
    #pragma unroll
    for (int c = 0; c < CDIM; ++c) { float xv = xs[nin][c]; s += xv*xv; }
    sq[node] = s;
  }
}

// ---------------- kNN: one row per wave, all state in registers -------------
// FROZEN round-1 kernel (measured r6: 115.5us, VGPR=60, WRITE=2MB). Every
// R=2 attempt (r2-r5) put the distance array in scratch (2GB WRITE, 7-11x
// slower). Flat d[32] + ~56 VGPR demand is the proven-promotable shape on
// this compiler. Do not increase per-thread state here.
#define KROWS 4
__device__ __forceinline__ unsigned long long packkey(float dv, int j) {
  unsigned ub = __float_as_uint(dv);
  ub ^= ((unsigned)((int)ub >> 31)) | 0x80000000u;   // monotone f32->u32
  return (((unsigned long long)ub) << 32) | (unsigned)j;
}

__global__ __launch_bounds__(256, 4) void knn_kernel(
    const float* __restrict__ x, const float* __restrict__ sq,
    int* __restrict__ idxOut) {
  __shared__ float sT16[CDIM][256];                 // transposed tile, 16 KB
  __shared__ unsigned long long skey[4][64];        // per-wave survivor keys
  __shared__ int scnt[4];
  const int tid  = threadIdx.x;
  const int lane = tid & 63;
  const int w    = tid >> 6;
  const int blocksPerGraph = NPTS / KROWS;          // 512
  const int g     = blockIdx.x / blocksPerGraph;
  const int rb    = (blockIdx.x % blocksPerGraph) * KROWS;
  const int gbase = g * NPTS;
  const int r0    = rb + w;                         // this wave's single row

  float tg[CDIM]; float tsq;
  {
    const float4* tp = (const float4*)(x + (size_t)(gbase + r0)*CDIM);
    float4 t0 = tp[0], t1 = tp[1], t2 = tp[2], t3 = tp[3];
    tg[0]=t0.x; tg[1]=t0.y; tg[2]=t0.z; tg[3]=t0.w;
    tg[4]=t1.x; tg[5]=t1.y; tg[6]=t1.z; tg[7]=t1.w;
    tg[8]=t2.x; tg[9]=t2.y; tg[10]=t2.z; tg[11]=t2.w;
    tg[12]=t3.x; tg[13]=t3.y; tg[14]=t3.z; tg[15]=t3.w;
    tsq = sq[gbase + r0];
  }

  float d[32];

  // prefetch tile 0 into regs
  float4 a0, a1, a2, a3;
  {
    const float4* xp = (const float4*)(x + (size_t)(gbase + tid)*CDIM);
    a0 = xp[0]; a1 = xp[1]; a2 = xp[2]; a3 = xp[3];
  }

  for (int t = 0; t < NPTS/256; ++t) {
    __syncthreads();                                // prev tile reads done
    sT16[0][tid]=a0.x;  sT16[1][tid]=a0.y;  sT16[2][tid]=a0.z;  sT16[3][tid]=a0.w;
    sT16[4][tid]=a1.x;  sT16[5][tid]=a1.y;  sT16[6][tid]=a1.z;  sT16[7][tid]=a1.w;
    sT16[8][tid]=a2.x;  sT16[9][tid]=a2.y;  sT16[10][tid]=a2.z; sT16[11][tid]=a2.w;
    sT16[12][tid]=a3.x; sT16[13][tid]=a3.y; sT16[14][tid]=a3.z; sT16[15][tid]=a3.w;
    __syncthreads();
    if (t < NPTS/256 - 1) {                         // issue next-tile loads early
      const float4* xp = (const float4*)(x + (size_t)(gbase + (t+1)*256 + tid)*CDIM);
      a0 = xp[0]; a1 = xp[1]; a2 = xp[2]; a3 = xp[3];
    }

    float4 sq4 = *(const float4*)(sq + gbase + t*256 + 4*lane);
    float sqv[4] = {sq4.x, sq4.y, sq4.z, sq4.w};

    float dot[4] = {0.f,0.f,0.f,0.f};
    #pragma unroll
    for (int c = 0; c < CDIM; ++c) {
      float4 cv = *(const float4*)(&sT16[c][4*lane]);
      float cvv[4]; cvv[0]=cv.x; cvv[1]=cv.y; cvv[2]=cv.z; cvv[3]=cv.w;
      float xv = tg[c];
      #pragma unroll
      for (int rr = 0; rr < 4; ++rr)
        dot[rr] += xv * cvv[rr];
    }
    #pragma unroll
    for (int rr = 0; rr < 4; ++rr)
      d[t*4 + rr] = tsq + sqv[rr] - 2.f*dot[rr];
  }

  {
    float lmin = d[0];
    #pragma unroll
    for (int s = 1; s < 32; ++s) lmin = fminf(lmin, d[s]);

    float v = lmin;
    #pragma unroll
    for (int k = 2; k <= 64; k <<= 1) {
      #pragma unroll
      for (int j = k >> 1; j > 0; j >>= 1) {
        float o = __shfl_xor(v, j);
        bool asc   = ((lane & k) == 0);
        bool lower = ((lane & j) == 0);
        float mn = fminf(v, o), mx = fmaxf(v, o);
        v = (asc == lower) ? mn : mx;
      }
    }
    float T = __shfl(v, 15);

    if (lane == 0) scnt[w] = 0;
    #pragma unroll
    for (int s = 0; s < 32; ++s) {
      if (d[s] <= T) {
        int p = atomicAdd(&scnt[w], 1);
        if (p < 64) {
          int j = (s >> 2)*256 + 4*lane + (s & 3);
          skey[w][p] = packkey(d[s], j);
        }
      }
    }
    int M = scnt[w];
    int row = gbase + r0;

    if (M <= 64) {
      unsigned long long key = (lane < M) ? skey[w][lane] : ~0ull;
      #pragma unroll
      for (int k = 2; k <= 64; k <<= 1) {
        #pragma unroll
        for (int j = k >> 1; j > 0; j >>= 1) {
          unsigned long long o = __shfl_xor(key, j);
          bool asc   = ((lane & k) == 0);
          bool lower = ((lane & j) == 0);
          unsigned long long mn = (key < o) ? key : o;
          unsigned long long mx = (key < o) ? o : key;
          key = (asc == lower) ? mn : mx;
        }
      }
      if (lane < KNN)
        idxOut[(size_t)row*KNN + lane] = gbase + (int)(key & 0xffffffffu);
    } else {
      for (int sel = 0; sel < KNN; ++sel) {
        unsigned long long lb = ~0ull;
        #pragma unroll
        for (int s = 0; s < 32; ++s) {
          int j = (s >> 2)*256 + 4*lane + (s & 3);
          unsigned long long ks = packkey(d[s], j);
          if (ks < lb) lb = ks;
        }
        #pragma unroll
        for (int off = 32; off > 0; off >>= 1) {
          unsigned long long o = __shfl_xor(lb, off);
          if (o < lb) lb = o;
        }
        if (lane == 0)
          idxOut[(size_t)row*KNN + sel] = gbase + (int)(lb & 0xffffffffu);
        #pragma unroll
        for (int s = 0; s < 32; ++s) {
          int j = (s >> 2)*256 + 4*lane + (s & 3);
          if (packkey(d[s], j) == lb) d[s] = FLT_MAX;
        }
      }
    }
  }
}

// ---------------- stats pass 1: per-channel sum/sumsq of h ------------------
// GROUPED: wave = 4 groups x 16 lanes; group owns an edge-quad (int4 idx),
// lane owns 4 channels (float4). No shuffles in the loop; one cross-group
// xor16+xor32 reduce per wave (each group's partial enters ONCE — no dup
// factor; see r7 post-mortem). VMEM/thread 132->24.
__global__ __launch_bounds__(256) void stats1_kernel(
    const float* __restrict__ P, const float* __restrict__ Q,
    const int* __restrict__ idx, float* __restrict__ pbuf) {
  int lane = threadIdx.x & 63;
  int wid  = threadIdx.x >> 6;
  int grp  = lane >> 4;                 // edge-quad slot 0..3
  int p    = lane & 15;                 // channel quad 0..15
  int gw   = blockIdx.x * 4 + wid;
  int n0 = gw * NPW;
  float4 s4  = {0.f,0.f,0.f,0.f};
  float4 ss4 = {0.f,0.f,0.f,0.f};
  #pragma unroll
  for (int ii = 0; ii < NPW; ++ii) {
    int i = n0 + ii;
    float4 q4 = *(const float4*)(Q + (size_t)i*ODIM + 4*p);
    int4 j4 = *(const int4*)(idx + (size_t)i*KNN + 4*grp);
    {
      float4 v = *(const float4*)(P + (size_t)j4.x*ODIM + 4*p);
      float hx=q4.x+v.x, hy=q4.y+v.y, hz=q4.z+v.z, hw=q4.w+v.w;
      s4.x+=hx; s4.y+=hy; s4.z+=hz; s4.w+=hw;
      ss4.x+=hx*hx; ss4.y+=hy*hy; ss4.z+=hz*hz; ss4.w+=hw*hw;
    }
    {
      float4 v = *(const float4*)(P + (size_t)j4.y*ODIM + 4*p);
      float hx=q4.x+v.x, hy=q4.y+v.y, hz=q4.z+v.z, hw=q4.w+v.w;
      s4.x+=hx; s4.y+=hy; s4.z+=hz; s4.w+=hw;
      ss4.x+=hx*hx; ss4.y+=hy*hy; ss4.z+=hz*hz; ss4.w+=hw*hw;
    }
    {
      float4 v = *(const float4*)(P + (size_t)j4.z*ODIM + 4*p);
      float hx=q4.x+v.x, hy=q4.y+v.y, hz=q4.z+v.z, hw=q4.w+v.w;
      s4.x+=hx; s4.y+=hy; s4.z+=hz; s4.w+=hw;
      ss4.x+=hx*hx; ss4.y+=hy*hy; ss4.z+=hz*hz; ss4.w+=hw*hw;
    }
    {
      float4 v = *(const float4*)(P + (size_t)j4.w*ODIM + 4*p);
      float hx=q4.x+v.x, hy=q4.y+v.y, hz=q4.z+v.z, hw=q4.w+v.w;
      s4.x+=hx; s4.y+=hy; s4.z+=hz; s4.w+=hw;
      ss4.x+=hx*hx; ss4.y+=hy*hy; ss4.z+=hz*hz; ss4.w+=hw*hw;
    }
  }
  // cross-group reduce (channels live on lanes p, p+16, p+32, p+48)
  s4.x  += __shfl_xor(s4.x,16);  s4.x  += __shfl_xor(s4.x,32);
  s4.y  += __shfl_xor(s4.y,16);  s4.y  += __shfl_xor(s4.y,32);
  s4.z  += __shfl_xor(s4.z,16);  s4.z  += __shfl_xor(s4.z,32);
  s4.w  += __shfl_xor(s4.w,16);  s4.w  += __shfl_xor(s4.w,32);
  ss4.x += __shfl_xor(ss4.x,16); ss4.x += __shfl_xor(ss4.x,32);
  ss4.y += __shfl_xor(ss4.y,16); ss4.y += __shfl_xor(ss4.y,32);
  ss4.z += __shfl_xor(ss4.z,16); ss4.z += __shfl_xor(ss4.z,32);
  ss4.w += __shfl_xor(ss4.w,16); ss4.w += __shfl_xor(ss4.w,32);
  __shared__ float ls[4][ODIM], lss[4][ODIM];
  if (grp == 0) {
    *(float4*)&ls[wid][4*p]  = s4;
    *(float4*)&lss[wid][4*p] = ss4;
  }
  __syncthreads();
  int tid = threadIdx.x;
  if (tid < ODIM) {
    float a = ls[0][tid] + ls[1][tid] + ls[2][tid] + ls[3][tid];
    pbuf[(size_t)tid*NBLK_E + blockIdx.x] = a;
  } else if (tid < 2*ODIM) {
    int o = tid - ODIM;
    float a = lss[0][o] + lss[1][o] + lss[2][o] + lss[3][o];
    pbuf[(size_t)(ODIM+o)*NBLK_E + blockIdx.x] = a;
  }
}

// 64 blocks x 1 wave: block o reduces channel o's sum & sumsq rows of pbuf
__global__ __launch_bounds__(64) void fin1_kernel(
    const float* __restrict__ pbuf,
    const float* __restrict__ g1, const float* __restrict__ be1,
    float* __restrict__ scale, float* __restrict__ shift) {
  int o = blockIdx.x, lane = threadIdx.x;
  const float* ps = pbuf + (size_t)o*NBLK_E;
  const float* pq = pbuf + (size_t)(ODIM+o)*NBLK_E;
  float s = 0.f, ss = 0.f;
  for (int t = lane; t < NBLK_E; t += 64) { s += ps[t]; ss += pq[t]; }
  #pragma unroll
  for (int off = 32; off > 0; off >>= 1) {
    s  += __shfl_xor(s, off);
    ss += __shfl_xor(ss, off);
  }
  if (lane == 0) {
    float mu  = s / (float)NEDGE;
    float var = ss / (float)NEDGE - mu*mu;
    float inv = 1.0f / sqrtf(var + EPSBN);
    float sc = g1[o] * inv;
    scale[o] = sc;
    shift[o] = be1[o] - mu * sc;
  }
}

// ---------------- stats pass 2: gate values + scalar sum/sumsq --------------
// GROUPED, r6-VERIFIED SEMANTICS (no partial scaling — each group's total
// enters the xor16/xor32 combine exactly once; the r7 *0.0625 "fix" was the
// correctness bug). Group owns an edge-quad (int4 idx), lane owns 4 channels.
__global__ __launch_bounds__(256) void stats2_kernel(
    const float* __restrict__ P, const float* __restrict__ Q,
    const int* __restrict__ idx, const float* __restrict__ scale,
    const float* __restrict__ shift, const float* __restrict__ Wg,
    const float* __restrict__ bg, float* __restrict__ gtbuf,
    float* __restrict__ gpart) {
  int lane = threadIdx.x & 63;
  int wid  = threadIdx.x >> 6;
  int grp  = lane >> 4;                 // edge-quad slot
  int p    = lane & 15;                 // channel quad
  int gw   = blockIdx.x * 4 + wid;
  int n0 = gw * NPW;
  float4 sc4 = *(const float4*)(scale + 4*p);
  float4 sh4 = *(const float4*)(shift + 4*p);
  float4 wg4 = *(const float4*)(Wg + 4*p);
  float bgv = bg[0];
  float s = 0.f, ss = 0.f;
  #pragma unroll
  for (int ii = 0; ii < NPW; ++ii) {
    int i = n0 + ii;
    float4 q4 = *(const float4*)(Q + (size_t)i*ODIM + 4*p);
    int4 j4 = *(const int4*)(idx + (size_t)i*KNN + 4*grp);
    #pragma unroll
    for (int e = 0; e < 4; ++e) {
      int j = (e==0) ? j4.x : (e==1) ? j4.y : (e==2) ? j4.z : j4.w;
      float4 p4 = *(const float4*)(P + (size_t)j*ODIM + 4*p);
      float zx = (q4.x + p4.x)*sc4.x + sh4.x;
      float zy = (q4.y + p4.y)*sc4.y + sh4.y;
      float zz = (q4.z + p4.z)*sc4.z + sh4.z;
      float zw = (q4.w + p4.w)*sc4.w + sh4.w;
      float v = (zx/(1.f+expf(-zx)))*wg4.x
              + (zy/(1.f+expf(-zy)))*wg4.y
              + (zz/(1.f+expf(-zz)))*wg4.z
              + (zw/(1.f+expf(-zw)))*wg4.w;
      v += __shfl_xor(v, 1);
      v += __shfl_xor(v, 2);
      v += __shfl_xor(v, 4);
      v += __shfl_xor(v, 8);            // group-wide sum over 64 channels
      float gt = v + bgv;
      if (p == 0) gtbuf[(size_t)i*KNN + 4*grp + e] = gt;
      s += gt; ss += gt*gt;             // per-group partial (dup across 16 lanes)
    }
  }
  // combine the 4 groups' partials: xor16/xor32 cross group boundaries only,
  // so each group's total is added exactly once -> every lane = wave total.
  s  += __shfl_xor(s, 16);  s  += __shfl_xor(s, 32);
  ss += __shfl_xor(ss, 16); ss += __shfl_xor(ss, 32);
  __shared__ float pw[4], pws[4];
  if (lane == 0) { pw[wid] = s; pws[wid] = ss; }
  __syncthreads();
  if (threadIdx.x == 0) {
    gpart[2*blockIdx.x]   = pw[0]+pw[1]+pw[2]+pw[3];
    gpart[2*blockIdx.x+1] = pws[0]+pws[1]+pws[2]+pws[3];
  }
}

// 1 block x 256: reduce 2048 (s,ss) pairs -> gate BN scale/shift
__global__ __launch_bounds__(256) void fin2_kernel(
    const float* __restrict__ gpart,
    const float* __restrict__ gg, const float* __restrict__ beg,
    float* __restrict__ gsc) {
  int tid = threadIdx.x;
  float s = 0.f, ss = 0.f;
  for (int t = tid; t < NBLK_E; t += 256) { s += gpart[2*t]; ss += gpart[2*t+1]; }
  __shared__ float as[256], bs[256];
  as[tid] = s; bs[tid] = ss;
  __syncthreads();
  #pragma unroll
  for (int st = 128; st > 0; st >>= 1) {
    if (tid < st) { as[tid] += as[tid+st]; bs[tid] += bs[tid+st]; }
    __syncthreads();
  }
  if (tid == 0) {
    float mu  = as[0] / (float)NEDGE;
    float var = bs[0] / (float)NEDGE - mu*mu;
    float inv = 1.f / sqrtf(var + EPSBN);
    float sg = gg[0] * inv;
    gsc[0] = sg; gsc[1] = beg[0] - mu * sg;
  }
}

// ---------------- final: hn, gate from gtbuf, softmax over K, weighted sum --
// GROUPED: 1 node per wave; group owns an edge-quad; lane owns 4 channels.
// Gate softmax via 4 cross-group shfl; output combined with 8 shfl,
// written by group 0. VMEM/thread ~49 -> ~8.
__global__ __launch_bounds__(256) void final_kernel(
    const float* __restrict__ P, const float* __restrict__ Q,
    const int* __restrict__ idx, const float* __restrict__ scale,
    const float* __restrict__ shift, const float* __restrict__ gtbuf,
    const float* __restrict__ gsc, float* __restrict__ out) {
  int lane = threadIdx.x & 63;
  int wid  = threadIdx.x >> 6;
  int grp  = lane >> 4;
  int p    = lane & 15;
  int i = blockIdx.x * 4 + wid;
  float4 sc4 = *(const float4*)(scale + 4*p);
  float4 sh4 = *(const float4*)(shift + 4*p);
  float gscale = gsc[0], gshift = gsc[1];
  float4 q4 = *(const float4*)(Q + (size_t)i*ODIM + 4*p);
  int4   j4 = *(const int4*)(idx + (size_t)i*KNN + 4*grp);
  float4 g4 = *(const float4*)(gtbuf + (size_t)i*KNN + 4*grp);

  // gate: BN + SiLU for this group's 4 edges
  float z0 = g4.x*gscale + gshift, z1 = g4.y*gscale + gshift;
  float z2 = g4.z*gscale + gshift, z3 = g4.w*gscale + gshift;
  float gt0 = z0/(1.f+expf(-z0)), gt1 = z1/(1.f+expf(-z1));
  float gt2 = z2/(1.f+expf(-z2)), gt3 = z3/(1.f+expf(-z3));
  float m = fmaxf(fmaxf(gt0, gt1), fmaxf(gt2, gt3));
  m = fmaxf(m, __shfl_xor(m, 16));
  m = fmaxf(m, __shfl_xor(m, 32));
  float e0 = expf(gt0-m), e1 = expf(gt1-m), e2 = expf(gt2-m), e3 = expf(gt3-m);
  float se = e0+e1+e2+e3;
  se += __shfl_xor(se, 16);
  se += __shfl_xor(se, 32);
  float invs = 1.f / se;
  float a0 = e0*invs, a1 = e1*invs, a2 = e2*invs, a3 = e3*invs;

  float4 acc = {0.f,0.f,0.f,0.f};
  {
    float4 v = *(const float4*)(P + (size_t)j4.x*ODIM + 4*p);
    float zx=(q4.x+v.x)*sc4.x+sh4.x, zy=(q4.y+v.y)*sc4.y+sh4.y;
    float zz=(q4.z+v.z)*sc4.z+sh4.z, zw=(q4.w+v.w)*sc4.w+sh4.w;
    acc.x += a0*(zx/(1.f+expf(-zx))); acc.y += a0*(zy/(1.f+expf(-zy)));
    acc.z += a0*(zz/(1.f+expf(-zz))); acc.w += a0*(zw/(1.f+expf(-zw)));
  }
  {
    float4 v = *(const float4*)(P + (size_t)j4.y*ODIM + 4*p);
    float zx=(q4.x+v.x)*sc4.x+sh4.x, zy=(q4.y+v.y)*sc4.y+sh4.y;
    float zz=(q4.z+v.z)*sc4.z+sh4.z, zw=(q4.w+v.w)*sc4.w+sh4.w;
    acc.x += a1*(zx/(1.f+expf(-zx))); acc.y += a1*(zy/(1.f+expf(-zy)));
    acc.z += a1*(zz/(1.f+expf(-zz))); acc.w += a1*(zw/(1.f+expf(-zw)));
  }
  {
    float4 v = *(const float4*)(P + (size_t)j4.z*ODIM + 4*p);
    float zx=(q4.x+v.x)*sc4.x+sh4.x, zy=(q4.y+v.y)*sc4.y+sh4.y;
    float zz=(q4.z+v.z)*sc4.z+sh4.z, zw=(q4.w+v.w)*sc4.w+sh4.w;
    acc.x += a2*(zx/(1.f+expf(-zx))); acc.y += a2*(zy/(1.f+expf(-zy)));
    acc.z += a2*(zz/(1.f+expf(-zz))); acc.w += a2*(zw/(1.f+expf(-zw)));
  }
  {
    float4 v = *(const float4*)(P + (size_t)j4.w*ODIM + 4*p);
    float zx=(q4.x+v.x)*sc4.x+sh4.x, zy=(q4.y+v.y)*sc4.y+sh4.y;
    float zz=(q4.z+v.z)*sc4.z+sh4.z, zw=(q4.w+v.w)*sc4.w+sh4.w;
    acc.x += a3*(zx/(1.f+expf(-zx))); acc.y += a3*(zy/(1.f+expf(-zy)));
    acc.z += a3*(zz/(1.f+expf(-zz))); acc.w += a3*(zw/(1.f+expf(-zw)));
  }
  // combine 4 groups' edge contributions
  acc.x += __shfl_xor(acc.x,16); acc.x += __shfl_xor(acc.x,32);
  acc.y += __shfl_xor(acc.y,16); acc.y += __shfl_xor(acc.y,32);
  acc.z += __shfl_xor(acc.z,16); acc.z += __shfl_xor(acc.z,32);
  acc.w += __shfl_xor(acc.w,16); acc.w += __shfl_xor(acc.w,32);
  if (grp == 0)
    *(float4*)(out + (size_t)i*ODIM + 4*p) = acc;
}

extern "C" void kernel_launch(void* const* d_in, const int* in_sizes, int n_in,
                              void* d_out, int out_size, void* d_ws, size_t ws_size,
                              hipStream_t stream) {
  const float* x   = (const float*)d_in[0];
  // d_in[1] = batch (unused: sorted equal-size graphs)
  const float* W1  = (const float*)d_in[2];
  const float* b1  = (const float*)d_in[3];
  const float* g1  = (const float*)d_in[4];
  const float* be1 = (const float*)d_in[5];
  const float* Wg  = (const float*)d_in[6];
  const float* bg  = (const float*)d_in[7];
  const float* gg  = (const float*)d_in[8];
  const float* beg = (const float*)d_in[9];
  float* out = (float*)d_out;

  char* ws = (char*)d_ws;
  int*   idx   = (int*)  (ws);                         // 2 MB
  float* P     = (float*)(ws + 2097152);               // 8 MB
  float* Q     = (float*)(ws + 10485760);              // 8 MB
  float* sq    = (float*)(ws + 18874368);              // 128 KB
  float* pbuf  = (float*)(ws + 19005440);              // 1 MB   [128][2048]
  float* gpart = (float*)(ws + 20054016);              // 16 KB  [2048][2]
  float* gtbuf = (float*)(ws + 20070400);              // 2 MB   [NEDGE]
  float* scale = (float*)(ws + 22167552);              // 64 f
  float* shift = (float*)(ws + 22167808);              // 64 f
  float* gsc   = (float*)(ws + 22168064);              // 2 f

  pq_kernel<<<NTOT/4, 256, 0, stream>>>(x, W1, b1, P, Q, sq);
  knn_kernel<<<NTOT/KROWS, 256, 0, stream>>>(x, sq, idx);
  stats1_kernel<<<NBLK_E, 256, 0, stream>>>(P, Q, idx, pbuf);
  fin1_kernel<<<ODIM, 64, 0, stream>>>(pbuf, g1, be1, scale, shift);
  stats2_kernel<<<NBLK_E, 256, 0, stream>>>(P, Q, idx, scale, shift, Wg, bg, gtbuf, gpart);
  fin2_kernel<<<1, 256, 0, stream>>>(gpart, gg, beg, gsc);
  final_kernel<<<NTOT/4, 256, 0, stream>>>(P, Q, idx, scale, shift, gtbuf, gsc, out);
}